// Round 1
// baseline (56.938 us; speedup 1.0000x reference)
//
#include <hip/hip_runtime.h>

#define C_S 384
#define C_H 128
#define C_Z 128
#define NROWS 512

// Kernel A: per-row  y = W·s + b  -> LayerNorm -> z = (Wout_half · ln)/D (+bout)
// bid < 512:  row of s1 with W1/b1, Wout[:, :128], add bout  -> u'
// bid >= 512: row of s2 with W2/b2, Wout[:, 128:], no bout   -> v
__global__ __launch_bounds__(128) void proj_ln_out(
    const float* __restrict__ s1, const float* __restrict__ s2,
    const float* __restrict__ W1, const float* __restrict__ b1,
    const float* __restrict__ W2, const float* __restrict__ b2,
    const float* __restrict__ gamma, const float* __restrict__ beta,
    const float* __restrict__ Wout, const float* __restrict__ bout,
    float* __restrict__ u, float* __restrict__ v)
{
    const int bid = blockIdx.x;
    const int t   = threadIdx.x;
    const bool isA = (bid < NROWS);
    const int r = isA ? bid : (bid - NROWS);
    const float* __restrict__ src  = isA ? s1 : s2;
    const float* __restrict__ W    = isA ? W1 : W2;
    const float* __restrict__ bias = isA ? b1 : b2;
    float* __restrict__ dst = isA ? u : v;
    const int wout_off = isA ? 0 : C_H;

    __shared__ float srow[C_S];
    __shared__ float red[C_H];
    __shared__ float lnv[C_H];

    // stage the 384-float input row (coalesced)
    srow[t]       = src[r * C_S + t];
    srow[t + 128] = src[r * C_S + t + 128];
    srow[t + 256] = src[r * C_S + t + 256];
    __syncthreads();

    // projection: thread t computes output channel t (K = 384)
    float y = bias[t];
    const float* wrow = W + t * C_S;
    #pragma unroll 8
    for (int k = 0; k < C_S; k += 4) {
        float4 w = *reinterpret_cast<const float4*>(wrow + k);
        y += w.x * srow[k] + w.y * srow[k + 1] + w.z * srow[k + 2] + w.w * srow[k + 3];
    }

    // LayerNorm across the 128 channels
    red[t] = y;
    __syncthreads();
    for (int s = 64; s > 0; s >>= 1) {
        if (t < s) red[t] += red[t + s];
        __syncthreads();
    }
    const float mu = red[0] * (1.0f / C_H);
    __syncthreads();
    const float d = y - mu;
    red[t] = d * d;
    __syncthreads();
    for (int s = 64; s > 0; s >>= 1) {
        if (t < s) red[t] += red[t + s];
        __syncthreads();
    }
    const float var = red[0] * (1.0f / C_H);
    lnv[t] = d * rsqrtf(var + 1e-5f) * gamma[t] + beta[t];
    __syncthreads();

    // output projection: thread t computes z = t over the 128 LN'd values
    const float invD = (float)(1.0 / (0.001 + 262144.0));
    float acc = 0.f;
    const float* wo = Wout + t * (2 * C_H) + wout_off;
    #pragma unroll 8
    for (int h = 0; h < C_H; h += 4) {
        float4 w = *reinterpret_cast<const float4*>(wo + h);
        acc += w.x * lnv[h] + w.y * lnv[h + 1] + w.z * lnv[h + 2] + w.w * lnv[h + 3];
    }
    dst[r * C_H + t] = acc * invD + (isA ? bout[t] : 0.f);
}

// Kernel B: out[n,m,z] = u'[n,z] + v[m,z]   (134 MB streaming write)
// grid: 512 n × 4 m-chunks; block 256: lanes 0-31 cover z (float4), tid/32 = m stagger.
__global__ __launch_bounds__(256) void bcast_add(
    const float* __restrict__ u, const float* __restrict__ v,
    float* __restrict__ out)
{
    const int n     = blockIdx.x >> 2;
    const int mbase = (blockIdx.x & 3) * 128;
    const int zq = threadIdx.x & 31;   // z / 4
    const int ml = threadIdx.x >> 5;   // 0..7

    const float4 u4 = reinterpret_cast<const float4*>(u + n * C_H)[zq];
    const float4* __restrict__ vq = reinterpret_cast<const float4*>(v);
    float4* __restrict__ oq = reinterpret_cast<float4*>(out)
                              + (size_t)n * 512 * 32 + (size_t)mbase * 32;

    #pragma unroll 4
    for (int m = ml; m < 128; m += 8) {
        float4 v4 = vq[(size_t)(mbase + m) * 32 + zq];
        float4 o;
        o.x = u4.x + v4.x;
        o.y = u4.y + v4.y;
        o.z = u4.z + v4.z;
        o.w = u4.w + v4.w;
        oq[(size_t)m * 32 + zq] = o;
    }
}

extern "C" void kernel_launch(void* const* d_in, const int* in_sizes, int n_in,
                              void* d_out, int out_size, void* d_ws, size_t ws_size,
                              hipStream_t stream) {
    const float* s1    = (const float*)d_in[0];
    const float* s2    = (const float*)d_in[1];
    const float* W1    = (const float*)d_in[2];
    const float* b1    = (const float*)d_in[3];
    const float* W2    = (const float*)d_in[4];
    const float* b2    = (const float*)d_in[5];
    const float* gamma = (const float*)d_in[6];
    const float* beta  = (const float*)d_in[7];
    const float* Wout  = (const float*)d_in[8];
    const float* bout  = (const float*)d_in[9];

    float* u = (float*)d_ws;                 // 512*128 fp32
    float* v = u + NROWS * C_H;              // 512*128 fp32

    proj_ln_out<<<2 * NROWS, 128, 0, stream>>>(s1, s2, W1, b1, W2, b2,
                                               gamma, beta, Wout, bout, u, v);
    bcast_add<<<NROWS * 4, 256, 0, stream>>>(u, v, (float*)d_out);
}